// Round 19
// baseline (458.161 us; speedup 1.0000x reference)
//
#include <hip/hip_runtime.h>
#include <hip/hip_bf16.h>
#include <stdint.h>

#define M_TOK 8192
#define KDIM  4096
#define NDIM  11008

typedef float  f32x4  __attribute__((ext_vector_type(4)));
typedef int    i32x4  __attribute__((ext_vector_type(4)));
typedef unsigned short ushort8 __attribute__((ext_vector_type(8)));

__device__ __forceinline__ unsigned short f2b(float f) {
    union { float f; unsigned int i; } v; v.f = f;
    unsigned int u = v.i;
    unsigned int r = (u + 0x7fffu + ((u >> 16) & 1u)) >> 16;
    return (unsigned short)r;
}
__device__ __forceinline__ float b2f(unsigned short u) {
    union { unsigned int i; float f; } v; v.i = ((unsigned int)u) << 16; return v.f;
}

__device__ __forceinline__ void gl_lds16(const void* g, void* l) {
    __builtin_amdgcn_global_load_lds(
        (const __attribute__((address_space(1))) unsigned int*)g,
        (__attribute__((address_space(3))) unsigned int*)l, 16, 0, 0);
}

// ---------------------------------------------------------------------------
// prep1 (round-15 verified): blocks 0..8191 rotate (+group max, vectorized
// contiguous-gather fast path), 8192..19199 qpack int32->i8.
// ---------------------------------------------------------------------------
__global__ __launch_bounds__(256) void prep1_kernel(
    const float* __restrict__ x, const float* __restrict__ R,
    const int* __restrict__ perm, const int* __restrict__ qw,
    unsigned short* __restrict__ xt, float* __restrict__ pmax,
    signed char* __restrict__ q8)
{
    const int bid = blockIdx.x;
    const int t   = threadIdx.x;

    if (bid < 8192) {
        __shared__ float Rs[16 * 273];
        __shared__ int   ps[256];
        const int bg = bid & 15;
        const int mc = bid >> 4;

        ps[t] = perm[bg * 256 + t];
        {
            const float* Rg = R + (size_t)bg * 4096;
#pragma unroll
            for (int k = 0; k < 16; ++k) {
                const int idx = t * 16 + k;
                const int bs = idx >> 8;
                const int i  = (idx >> 4) & 15;
                const int j  = idx & 15;
                Rs[bs * 273 + i * 17 + j] = Rg[idx];
            }
        }
        __syncthreads();

        const int bs = t & 15;
        const int r  = t >> 4;
        const int m  = mc * 16 + r;
        const float* xrow = x + (size_t)m * KDIM;

        const int base = ps[bs * 16];
        bool contig = (base & 3) == 0;
#pragma unroll
        for (int i = 1; i < 16; ++i) contig &= (ps[bs * 16 + i] == base + i);

        float xv[16];
        if (contig) {
            const f32x4* xp = (const f32x4*)(xrow + base);
            const f32x4 a0 = xp[0], a1 = xp[1], a2 = xp[2], a3 = xp[3];
#pragma unroll
            for (int i = 0; i < 4; ++i) {
                xv[i]      = a0[i];
                xv[4 + i]  = a1[i];
                xv[8 + i]  = a2[i];
                xv[12 + i] = a3[i];
            }
        } else {
#pragma unroll
            for (int i = 0; i < 16; ++i) xv[i] = xrow[ps[bs * 16 + i]];
        }

        float o[16];
#pragma unroll
        for (int j = 0; j < 16; ++j) o[j] = 0.f;
#pragma unroll
        for (int i = 0; i < 16; ++i) {
            const float xi = xv[i];
            const float* Rrow = &Rs[bs * 273 + i * 17];
#pragma unroll
            for (int j = 0; j < 16; ++j) o[j] += xi * Rrow[j];
        }

        float lm = 0.f;
#pragma unroll
        for (int j = 0; j < 16; ++j) lm = fmaxf(lm, fabsf(o[j]));
#pragma unroll
        for (int k = 1; k < 16; k <<= 1) lm = fmaxf(lm, __shfl_xor(lm, k, 64));
        if (bs == 0) pmax[(size_t)m * 16 + bg] = lm;

        unsigned short os[16] __attribute__((aligned(16)));
#pragma unroll
        for (int j = 0; j < 16; ++j) os[j] = f2b(o[j]);
        unsigned short* dst = xt + (size_t)m * KDIM + bg * 256 + bs * 16;
        *(ushort8*)dst       = *(ushort8*)os;
        *(ushort8*)(dst + 8) = *(ushort8*)(os + 8);
    } else {
        const size_t base = ((size_t)(bid - 8192) * 256 + t) * 16;
        const int4* qp = (const int4*)(qw + base);
        signed char o[16] __attribute__((aligned(16)));
#pragma unroll
        for (int c = 0; c < 4; ++c) {
            const int4 v = qp[c];
            o[c*4+0] = (signed char)v.x; o[c*4+1] = (signed char)v.y;
            o[c*4+2] = (signed char)v.z; o[c*4+3] = (signed char)v.w;
        }
        *(int4*)(q8 + base) = *(const int4*)o;
    }
}

// ---------------------------------------------------------------------------
// Pack (round-12 verified): per-row amax -> s_a[m]; bf16 -> i8; S[m].
// ---------------------------------------------------------------------------
__global__ __launch_bounds__(256) void pack_kernel(
    const unsigned short* __restrict__ xt, const float* __restrict__ pmax,
    signed char* __restrict__ xt8, int* __restrict__ S, float* __restrict__ sa)
{
    const int m = blockIdx.x;
    const int t = threadIdx.x;

    float am = 1e-20f;
#pragma unroll
    for (int i = 0; i < 16; ++i) am = fmaxf(am, pmax[(size_t)m * 16 + i]);
    const float inv = 127.0f / am;

    const unsigned short* src = xt + (size_t)m * KDIM + t * 16;
    ushort8 u0 = *(const ushort8*)src;
    ushort8 u1 = *(const ushort8*)(src + 8);
    signed char qv[16] __attribute__((aligned(16)));
    int s = 0;
#pragma unroll
    for (int i = 0; i < 8; ++i) {
        int q0 = (int)rintf(b2f(u0[i]) * inv);
        q0 = q0 > 127 ? 127 : (q0 < -127 ? -127 : q0);
        qv[i] = (signed char)q0; s += q0;
        int q1 = (int)rintf(b2f(u1[i]) * inv);
        q1 = q1 > 127 ? 127 : (q1 < -127 ? -127 : q1);
        qv[8 + i] = (signed char)q1; s += q1;
    }
    *(int4*)(xt8 + (size_t)m * KDIM + t * 16) = *(const int4*)qv;

#pragma unroll
    for (int k = 1; k < 64; k <<= 1) s += __shfl_xor(s, k, 64);
    __shared__ int ws[4];
    if ((t & 63) == 0) ws[t >> 6] = s;
    __syncthreads();
    if (t == 0) {
        S[m]  = ws[0] + ws[1] + ws[2] + ws[3];
        sa[m] = am * (1.0f / 127.0f);
    }
}

// ---------------------------------------------------------------------------
// i8 GEMM, 128x128 tile, BK=128: LDS 64 KiB -> 2 INDEPENDENT blocks/CU
// (cross-block overlap hides the barrier/LDS serialization that pins the
// 256x256 1-block/CU version at MfmaUtil ~50). 128-B rows keep the proven
// 0-conflict XOR-swizzle geometry (64-B rows are structurally conflicted —
// round 17). 256 threads = 4 waves (2x2); per wave 64x64 out, 32 MFMA/K-tile.
// Same verified TILE discipline: B-next staged early (4), A+2 late (4),
// counted WAITV(4), 2 barriers/K-tile. Uniform 5504-block grid (no tail).
// ---------------------------------------------------------------------------
#define BAR() do { asm volatile("" ::: "memory"); __builtin_amdgcn_s_barrier(); \
                   asm volatile("" ::: "memory"); } while (0)
#define WAITV(n) asm volatile("s_waitcnt vmcnt(" #n ")" ::: "memory")
#define PRIO1 __builtin_amdgcn_s_setprio(1)
#define PRIO0 __builtin_amdgcn_s_setprio(0)

#define ABASE(bb) ((bb)*32768)
#define BBASE(bb) ((bb)*32768 + 16384)

#define STAGE_A(bb, kB) do { \
    gl_lds16(aStageBase + (size_t)( 0)*KDIM + (kB), lds + ABASE(bb) +     0 + wOff); \
    gl_lds16(aStageBase + (size_t)(32)*KDIM + (kB), lds + ABASE(bb) +  4096 + wOff); \
    gl_lds16(aStageBase + (size_t)(64)*KDIM + (kB), lds + ABASE(bb) +  8192 + wOff); \
    gl_lds16(aStageBase + (size_t)(96)*KDIM + (kB), lds + ABASE(bb) + 12288 + wOff); \
} while (0)
#define STAGE_B(bb, kB) do { \
    gl_lds16(bStageBase + (size_t)( 0)*KDIM + (kB), lds + BBASE(bb) +     0 + wOff); \
    gl_lds16(bStageBase + (size_t)(32)*KDIM + (kB), lds + BBASE(bb) +  4096 + wOff); \
    gl_lds16(bStageBase + (size_t)(64)*KDIM + (kB), lds + BBASE(bb) +  8192 + wOff); \
    gl_lds16(bStageBase + (size_t)(96)*KDIM + (kB), lds + BBASE(bb) + 12288 + wOff); \
} while (0)

#define PH_READ_A(bb) do { \
    _Pragma("unroll") \
    for (int mf = 0; mf < 4; ++mf) { \
        aF[mf][0] = *(const i32x4*)(lds + ABASE(bb) + aRdBase + (mf*16)*128 + cs0); \
        aF[mf][1] = *(const i32x4*)(lds + ABASE(bb) + aRdBase + (mf*16)*128 + cs1); \
    } \
} while (0)
#define PH_READ_B(bb) do { \
    _Pragma("unroll") \
    for (int nf = 0; nf < 4; ++nf) { \
        bF[nf][0] = *(const i32x4*)(lds + BBASE(bb) + bRdBase + (nf*16)*128 + cs0); \
        bF[nf][1] = *(const i32x4*)(lds + BBASE(bb) + bRdBase + (nf*16)*128 + cs1); \
    } \
} while (0)

#define MFMA_H(h) do { \
    _Pragma("unroll") \
    for (int mf = 0; mf < 4; ++mf) \
    _Pragma("unroll") \
    for (int nf = 0; nf < 4; ++nf) \
        acc[mf][nf] = __builtin_amdgcn_mfma_i32_16x16x64_i8( \
            aF[mf][h], bF[nf][h], acc[mf][nf], 0, 0, 0); \
} while (0)

// MODE 0: steady; 1: t=nt-2 (stage B-next only, drain); 2: last (compute)
#define TILE(bb, kB, MODE) do { \
    PH_READ_A(bb); PH_READ_B(bb); \
    if ((MODE) <= 1) STAGE_B((bb)^1, (kB) + 128); \
    PRIO1; MFMA_H(0); PRIO0; \
    BAR(); \
    if ((MODE) == 0) STAGE_A(bb, (kB) + 256); \
    PRIO1; MFMA_H(1); PRIO0; \
    if ((MODE) == 0) WAITV(4); \
    if ((MODE) == 1) WAITV(0); \
    BAR(); \
} while (0)

__global__ __launch_bounds__(256, 2) void gemm_all(
    const signed char* __restrict__ Aq, const signed char* __restrict__ Bq,
    const float* __restrict__ sn, const float* __restrict__ zz,
    const float* __restrict__ sa, const int* __restrict__ S,
    float* __restrict__ C)
{
    __shared__ char lds[65536];

    const int tid  = threadIdx.x;
    const int wave = tid >> 6;
    const int lane = tid & 63;
    const int wr   = wave >> 1;      // 0..1 (M)
    const int wc   = wave & 1;       // 0..1 (N)
    const int wg   = blockIdx.x;

    // XCD chunking: 5504 = 8 * 688. Supertile: 8-tn stripes (last 6-wide),
    // within-stripe tm*W+tn so ~64 consecutive ids (2 blocks/CU x 32 CU per
    // XCD) form an 8tm x 8tn window (16 x 0.5 MB panels, L3-resident).
    const int swz = (wg & 7) * 688 + (wg >> 3);
    int tm, tn;
    if (swz < 5120) {                 // stripes 0..9: tn 8S..8S+7
        const int Sx = swz >> 9;
        const int L  = swz & 511;
        tm = L >> 3;
        tn = (Sx << 3) + (L & 7);
    } else {                          // stripe 10: tn 80..85 (6-wide)
        const int L = swz - 5120;     // 0..383
        tm = L / 6;
        tn = 80 + (L - tm * 6);
    }

    // staging: thread t -> row t>>3 (0..31), 16-B chunk t&7; 4 loads cover
    // 128 rows. Pre-swizzled global source (row&7 == sRow&7 for all loads).
    const int sRow    = tid >> 3;
    const int gColSwz = (((tid & 7) ^ (sRow & 7)) << 4);
    const char* aStageBase = (const char*)Aq + (size_t)(tm * 128 + sRow) * KDIM + gColSwz;
    const char* bStageBase = (const char*)Bq + (size_t)(tn * 128 + sRow) * KDIM + gColSwz;
    const int wOff = wave * 1024;

    // ds_read addressing (swizzled, 128-B rows — round-12 verified algebra)
    const int lane15 = lane & 15;
    const int lx  = (lane & 7) << 4;
    const int kq  = (lane >> 4) * 16;
    const int cs0 = kq ^ lx;            // k 0..63
    const int cs1 = (kq + 64) ^ lx;     // k 64..127
    const int aRdBase = wr * 8192 + lane15 * 128;   // wr*64 rows
    const int bRdBase = wc * 8192 + lane15 * 128;   // wc*64 cols

    i32x4 acc[4][4] = {};
    i32x4 aF[4][2];
    i32x4 bF[4][2];

    // prologue: A0,B0 + A1; WAITV(4) leaves A1 in flight
    STAGE_A(0, 0);
    STAGE_B(0, 0);
    STAGE_A(1, 128);
    WAITV(4);
    BAR();

    int kB = 0;
#pragma unroll 1
    for (int t = 0; t < 29; t += 2) {   // 32 K-tiles of BK=128
        TILE(0, kB, 0);
        TILE(1, kB + 128, 0);
        kB += 256;
    }
    TILE(0, 30 * 128, 1);
    TILE(1, 31 * 128, 2);

    // epilogue: C/D col = lane&15, row = (lane>>4)*4 + reg
    const int row0 = tm * 128 + wr * 64 + (lane >> 4) * 4;
    const int col0 = tn * 128 + wc * 64 + lane15;
    float sn4[4], z4[4];
#pragma unroll
    for (int ni = 0; ni < 4; ++ni) { sn4[ni] = sn[col0 + ni*16]; z4[ni] = zz[col0 + ni*16]; }
#pragma unroll
    for (int mi = 0; mi < 4; ++mi) {
        const int rbase = row0 + mi * 16;
        float sa4[4], Sf4[4];
#pragma unroll
        for (int j = 0; j < 4; ++j) { sa4[j] = sa[rbase + j]; Sf4[j] = (float)S[rbase + j]; }
#pragma unroll
        for (int ni = 0; ni < 4; ++ni) {
            const i32x4 v = acc[mi][ni];
            const int c = col0 + ni * 16;
#pragma unroll
            for (int j = 0; j < 4; ++j)
                C[(size_t)(rbase + j) * NDIM + c] = sa4[j] * sn4[ni] * ((float)v[j] - z4[ni] * Sf4[j]);
        }
    }
}

extern "C" void kernel_launch(void* const* d_in, const int* in_sizes, int n_in,
                              void* d_out, int out_size, void* d_ws, size_t ws_size,
                              hipStream_t stream) {
    const float* x      = (const float*)d_in[0];
    const float* R      = (const float*)d_in[1];
    const float* scales = (const float*)d_in[2];
    const float* zeros  = (const float*)d_in[3];
    const int*   perm   = (const int*)d_in[4];
    const int*   qw     = (const int*)d_in[5];
    float*       out    = (float*)d_out;

    // workspace layout (bytes)
    char* ws = (char*)d_ws;
    unsigned short* xt16 = (unsigned short*)ws;                   //  64 MiB @ 0
    signed char*    xt8  = (signed char*)(ws + 67108864);         //  32 MiB
    signed char*    q8   = (signed char*)(ws + 100663296);        //  43 MiB
    float*          pmax = (float*)(ws + 145752064);              // 512 KiB
    float*          sa   = (float*)(ws + 146276352);              //  32 KiB
    int*            S    = (int*)(ws + 146309120);                //  32 KiB

    prep1_kernel<<<dim3(8192 + 11008), 256, 0, stream>>>(x, R, perm, qw, xt16, pmax, q8);
    pack_kernel<<<dim3(M_TOK), 256, 0, stream>>>(xt16, pmax, xt8, S, sa);
    gemm_all<<<dim3((M_TOK / 128) * (NDIM / 128)), 256, 0, stream>>>(xt8, q8, scales, zeros, sa, S, out);
}

// Round 20
// 443.862 us; speedup vs baseline: 1.0322x; 1.0322x over previous
//
#include <hip/hip_runtime.h>
#include <hip/hip_bf16.h>
#include <stdint.h>

#define M_TOK 8192
#define KDIM  4096
#define NDIM  11008

typedef float  f32x4  __attribute__((ext_vector_type(4)));
typedef int    i32x4  __attribute__((ext_vector_type(4)));
typedef unsigned short ushort8 __attribute__((ext_vector_type(8)));

__device__ __forceinline__ unsigned short f2b(float f) {
    union { float f; unsigned int i; } v; v.f = f;
    unsigned int u = v.i;
    unsigned int r = (u + 0x7fffu + ((u >> 16) & 1u)) >> 16;
    return (unsigned short)r;
}
__device__ __forceinline__ float b2f(unsigned short u) {
    union { unsigned int i; float f; } v; v.i = ((unsigned int)u) << 16; return v.f;
}

__device__ __forceinline__ void gl_lds16(const void* g, void* l) {
    __builtin_amdgcn_global_load_lds(
        (const __attribute__((address_space(1))) unsigned int*)g,
        (__attribute__((address_space(3))) unsigned int*)l, 16, 0, 0);
}

// ---------------------------------------------------------------------------
// prep1 (round-15 verified): blocks 0..8191 rotate (+group max, vectorized
// contiguous-gather fast path), 8192..19199 qpack int32->i8.
// ---------------------------------------------------------------------------
__global__ __launch_bounds__(256) void prep1_kernel(
    const float* __restrict__ x, const float* __restrict__ R,
    const int* __restrict__ perm, const int* __restrict__ qw,
    unsigned short* __restrict__ xt, float* __restrict__ pmax,
    signed char* __restrict__ q8)
{
    const int bid = blockIdx.x;
    const int t   = threadIdx.x;

    if (bid < 8192) {
        __shared__ float Rs[16 * 273];
        __shared__ int   ps[256];
        const int bg = bid & 15;
        const int mc = bid >> 4;

        ps[t] = perm[bg * 256 + t];
        {
            const float* Rg = R + (size_t)bg * 4096;
#pragma unroll
            for (int k = 0; k < 16; ++k) {
                const int idx = t * 16 + k;
                const int bs = idx >> 8;
                const int i  = (idx >> 4) & 15;
                const int j  = idx & 15;
                Rs[bs * 273 + i * 17 + j] = Rg[idx];
            }
        }
        __syncthreads();

        const int bs = t & 15;
        const int r  = t >> 4;
        const int m  = mc * 16 + r;
        const float* xrow = x + (size_t)m * KDIM;

        const int base = ps[bs * 16];
        bool contig = (base & 3) == 0;
#pragma unroll
        for (int i = 1; i < 16; ++i) contig &= (ps[bs * 16 + i] == base + i);

        float xv[16];
        if (contig) {
            const f32x4* xp = (const f32x4*)(xrow + base);
            const f32x4 a0 = xp[0], a1 = xp[1], a2 = xp[2], a3 = xp[3];
#pragma unroll
            for (int i = 0; i < 4; ++i) {
                xv[i]      = a0[i];
                xv[4 + i]  = a1[i];
                xv[8 + i]  = a2[i];
                xv[12 + i] = a3[i];
            }
        } else {
#pragma unroll
            for (int i = 0; i < 16; ++i) xv[i] = xrow[ps[bs * 16 + i]];
        }

        float o[16];
#pragma unroll
        for (int j = 0; j < 16; ++j) o[j] = 0.f;
#pragma unroll
        for (int i = 0; i < 16; ++i) {
            const float xi = xv[i];
            const float* Rrow = &Rs[bs * 273 + i * 17];
#pragma unroll
            for (int j = 0; j < 16; ++j) o[j] += xi * Rrow[j];
        }

        float lm = 0.f;
#pragma unroll
        for (int j = 0; j < 16; ++j) lm = fmaxf(lm, fabsf(o[j]));
#pragma unroll
        for (int k = 1; k < 16; k <<= 1) lm = fmaxf(lm, __shfl_xor(lm, k, 64));
        if (bs == 0) pmax[(size_t)m * 16 + bg] = lm;

        unsigned short os[16] __attribute__((aligned(16)));
#pragma unroll
        for (int j = 0; j < 16; ++j) os[j] = f2b(o[j]);
        unsigned short* dst = xt + (size_t)m * KDIM + bg * 256 + bs * 16;
        *(ushort8*)dst       = *(ushort8*)os;
        *(ushort8*)(dst + 8) = *(ushort8*)(os + 8);
    } else {
        const size_t base = ((size_t)(bid - 8192) * 256 + t) * 16;
        const int4* qp = (const int4*)(qw + base);
        signed char o[16] __attribute__((aligned(16)));
#pragma unroll
        for (int c = 0; c < 4; ++c) {
            const int4 v = qp[c];
            o[c*4+0] = (signed char)v.x; o[c*4+1] = (signed char)v.y;
            o[c*4+2] = (signed char)v.z; o[c*4+3] = (signed char)v.w;
        }
        *(int4*)(q8 + base) = *(const int4*)o;
    }
}

// ---------------------------------------------------------------------------
// Pack (round-12 verified): per-row amax -> s_a[m]; bf16 -> i8; S[m].
// ---------------------------------------------------------------------------
__global__ __launch_bounds__(256) void pack_kernel(
    const unsigned short* __restrict__ xt, const float* __restrict__ pmax,
    signed char* __restrict__ xt8, int* __restrict__ S, float* __restrict__ sa)
{
    const int m = blockIdx.x;
    const int t = threadIdx.x;

    float am = 1e-20f;
#pragma unroll
    for (int i = 0; i < 16; ++i) am = fmaxf(am, pmax[(size_t)m * 16 + i]);
    const float inv = 127.0f / am;

    const unsigned short* src = xt + (size_t)m * KDIM + t * 16;
    ushort8 u0 = *(const ushort8*)src;
    ushort8 u1 = *(const ushort8*)(src + 8);
    signed char qv[16] __attribute__((aligned(16)));
    int s = 0;
#pragma unroll
    for (int i = 0; i < 8; ++i) {
        int q0 = (int)rintf(b2f(u0[i]) * inv);
        q0 = q0 > 127 ? 127 : (q0 < -127 ? -127 : q0);
        qv[i] = (signed char)q0; s += q0;
        int q1 = (int)rintf(b2f(u1[i]) * inv);
        q1 = q1 > 127 ? 127 : (q1 < -127 ? -127 : q1);
        qv[8 + i] = (signed char)q1; s += q1;
    }
    *(int4*)(xt8 + (size_t)m * KDIM + t * 16) = *(const int4*)qv;

#pragma unroll
    for (int k = 1; k < 64; k <<= 1) s += __shfl_xor(s, k, 64);
    __shared__ int ws[4];
    if ((t & 63) == 0) ws[t >> 6] = s;
    __syncthreads();
    if (t == 0) {
        S[m]  = ws[0] + ws[1] + ws[2] + ws[3];
        sa[m] = am * (1.0f / 127.0f);
    }
}

// ---------------------------------------------------------------------------
// i8 GEMM, 256x256 tile, BK=128, 4 WAVES with 128x128-per-wave output
// (ILP experiment): reads/MFMA drops 0.375 -> 0.125 so the LDS-read pipe
// (co-critical at ~2300 cyc/K-tile in the 8-wave version, sum-not-max with
// MFMA) falls below the MFMA pipe. acc 8x8 i32x4 = 256 VGPR + 128 frag
// VGPRs -> 1 wave/SIMD; __launch_bounds__(256,1) (no VGPR clamp).
// Same verified 0-conflict 128-B-row swizzle, TILE/vmcnt discipline
// (counted WAITV(8), never 0 mid-loop), 2 barriers/K-tile.
// ---------------------------------------------------------------------------
#define BAR() do { asm volatile("" ::: "memory"); __builtin_amdgcn_s_barrier(); \
                   asm volatile("" ::: "memory"); } while (0)
#define WAITV(n) asm volatile("s_waitcnt vmcnt(" #n ")" ::: "memory")
#define PRIO1 __builtin_amdgcn_s_setprio(1)
#define PRIO0 __builtin_amdgcn_s_setprio(0)

// LDS: A0@0(32K) B0@32K | A1@64K B1@96K
#define ABASE(bb) ((bb)*65536)
#define BBASE(bb) ((bb)*65536 + 32768)

#define STAGE8(basePtr, kB, ldsOff) do { \
    gl_lds16(basePtr + (size_t)(  0)*KDIM + (kB), lds + (ldsOff) +     0 + wOff); \
    gl_lds16(basePtr + (size_t)( 32)*KDIM + (kB), lds + (ldsOff) +  4096 + wOff); \
    gl_lds16(basePtr + (size_t)( 64)*KDIM + (kB), lds + (ldsOff) +  8192 + wOff); \
    gl_lds16(basePtr + (size_t)( 96)*KDIM + (kB), lds + (ldsOff) + 12288 + wOff); \
    gl_lds16(basePtr + (size_t)(128)*KDIM + (kB), lds + (ldsOff) + 16384 + wOff); \
    gl_lds16(basePtr + (size_t)(160)*KDIM + (kB), lds + (ldsOff) + 20480 + wOff); \
    gl_lds16(basePtr + (size_t)(192)*KDIM + (kB), lds + (ldsOff) + 24576 + wOff); \
    gl_lds16(basePtr + (size_t)(224)*KDIM + (kB), lds + (ldsOff) + 28672 + wOff); \
} while (0)
#define STAGE_A(bb, kB) STAGE8(aStageBase, kB, ABASE(bb))
#define STAGE_B(bb, kB) STAGE8(bStageBase, kB, BBASE(bb))

#define PH_READ_A(bb) do { \
    _Pragma("unroll") \
    for (int mf = 0; mf < 8; ++mf) { \
        aF[mf][0] = *(const i32x4*)(lds + ABASE(bb) + aRdBase + mf*2048 + cs0); \
        aF[mf][1] = *(const i32x4*)(lds + ABASE(bb) + aRdBase + mf*2048 + cs1); \
    } \
} while (0)
#define PH_READ_B(bb) do { \
    _Pragma("unroll") \
    for (int nf = 0; nf < 8; ++nf) { \
        bF[nf][0] = *(const i32x4*)(lds + BBASE(bb) + bRdBase + nf*2048 + cs0); \
        bF[nf][1] = *(const i32x4*)(lds + BBASE(bb) + bRdBase + nf*2048 + cs1); \
    } \
} while (0)

#define MFMA_H(h) do { \
    _Pragma("unroll") \
    for (int mf = 0; mf < 8; ++mf) \
    _Pragma("unroll") \
    for (int nf = 0; nf < 8; ++nf) \
        acc[mf][nf] = __builtin_amdgcn_mfma_i32_16x16x64_i8( \
            aF[mf][h], bF[nf][h], acc[mf][nf], 0, 0, 0); \
} while (0)

// MODE 0: steady; 1: t=nt-2 (stage B-next only, drain); 2: last (compute)
#define TILE(bb, kB, MODE) do { \
    PH_READ_A(bb); PH_READ_B(bb); \
    if ((MODE) <= 1) STAGE_B((bb)^1, (kB) + 128); \
    PRIO1; MFMA_H(0); PRIO0; \
    BAR(); \
    if ((MODE) == 0) STAGE_A(bb, (kB) + 256); \
    PRIO1; MFMA_H(1); PRIO0; \
    if ((MODE) == 0) WAITV(8); \
    if ((MODE) == 1) WAITV(0); \
    BAR(); \
} while (0)

// ---- tail (128x256): wave tile 64x128; A 4 loads, B 8 loads ----
#define TAB(bb) ((bb)*49152)
#define TBB(bb) ((bb)*49152 + 16384)

#define STAGE_TA(bb, kB) do { \
    gl_lds16(aStageBase + (size_t)( 0)*KDIM + (kB), lds + TAB(bb) +     0 + wOff); \
    gl_lds16(aStageBase + (size_t)(32)*KDIM + (kB), lds + TAB(bb) +  4096 + wOff); \
    gl_lds16(aStageBase + (size_t)(64)*KDIM + (kB), lds + TAB(bb) +  8192 + wOff); \
    gl_lds16(aStageBase + (size_t)(96)*KDIM + (kB), lds + TAB(bb) + 12288 + wOff); \
} while (0)
#define STAGE_TB(bb, kB) STAGE8(bStageBase, kB, TBB(bb))

#define PH_READ_TA(bb) do { \
    _Pragma("unroll") \
    for (int mf = 0; mf < 4; ++mf) { \
        aF[mf][0] = *(const i32x4*)(lds + TAB(bb) + aRdBase + mf*2048 + cs0); \
        aF[mf][1] = *(const i32x4*)(lds + TAB(bb) + aRdBase + mf*2048 + cs1); \
    } \
} while (0)
#define PH_READ_TB(bb) do { \
    _Pragma("unroll") \
    for (int nf = 0; nf < 8; ++nf) { \
        bF[nf][0] = *(const i32x4*)(lds + TBB(bb) + bRdBase + nf*2048 + cs0); \
        bF[nf][1] = *(const i32x4*)(lds + TBB(bb) + bRdBase + nf*2048 + cs1); \
    } \
} while (0)

#define MFMA_TH(h) do { \
    _Pragma("unroll") \
    for (int mf = 0; mf < 4; ++mf) \
    _Pragma("unroll") \
    for (int nf = 0; nf < 8; ++nf) \
        acc[mf][nf] = __builtin_amdgcn_mfma_i32_16x16x64_i8( \
            aF[mf][h], bF[nf][h], acc[mf][nf], 0, 0, 0); \
} while (0)

#define TTILE(bb, kB, MODE) do { \
    PH_READ_TA(bb); PH_READ_TB(bb); \
    if ((MODE) <= 1) STAGE_TB((bb)^1, (kB) + 128); \
    PRIO1; MFMA_TH(0); PRIO0; \
    BAR(); \
    if ((MODE) == 0) STAGE_TA(bb, (kB) + 256); \
    PRIO1; MFMA_TH(1); PRIO0; \
    if ((MODE) == 0) WAITV(4); \
    if ((MODE) == 1) WAITV(0); \
    BAR(); \
} while (0)

__global__ __launch_bounds__(256, 1) void gemm_all(
    const signed char* __restrict__ Aq, const signed char* __restrict__ Bq,
    const float* __restrict__ sn, const float* __restrict__ zz,
    const float* __restrict__ sa, const int* __restrict__ S,
    float* __restrict__ C)
{
    __shared__ char lds[131072];

    const int tid  = threadIdx.x;
    const int wave = tid >> 6;
    const int lane = tid & 63;
    const int wr   = wave >> 1;      // 0..1 (M)
    const int wc   = wave & 1;       // 0..1 (N)
    const int wg   = blockIdx.x;

    // staging addressing: thread t -> row t>>3 (0..31), 16-B chunk t&7;
    // pre-swizzled global source (XOR involution on row&7)
    const int sRow    = tid >> 3;
    const int gColSwz = (((tid & 7) ^ (sRow & 7)) << 4);
    const int wOff    = wave * 1024;

    // ds_read addressing (swizzled 128-B rows, round-12 verified algebra)
    const int lane15 = lane & 15;
    const int lx  = (lane & 7) << 4;
    const int kq  = (lane >> 4) * 16;
    const int cs0 = kq ^ lx;            // k 0..63
    const int cs1 = (kq + 64) ^ lx;     // k 64..127

    if (wg < 1280) {
        // ============ MAIN: 256x256, tn 0..39 (5 clean rounds) ============
        const int swz = (wg & 7) * 160 + (wg >> 3);
        const int Sx = swz >> 7;
        const int L  = swz & 127;
        const int tm = L >> 2;
        const int tn = (Sx << 2) + (L & 3);

        const char* aStageBase = (const char*)Aq + (size_t)(tm * 256 + sRow) * KDIM + gColSwz;
        const char* bStageBase = (const char*)Bq + (size_t)(tn * 256 + sRow) * KDIM + gColSwz;

        const int aRdBase = wr * 16384 + lane15 * 128;   // wr*128 rows
        const int bRdBase = wc * 16384 + lane15 * 128;   // wc*128 cols

        i32x4 acc[8][8] = {};
        i32x4 aF[8][2];
        i32x4 bF[8][2];

        STAGE_A(0, 0);
        STAGE_B(0, 0);
        STAGE_A(1, 128);
        WAITV(8);
        BAR();

        int kB = 0;
#pragma unroll 1
        for (int t = 0; t < 29; t += 2) {   // 32 K-tiles of BK=128
            TILE(0, kB, 0);
            TILE(1, kB + 128, 0);
            kB += 256;
        }
        TILE(0, 30 * 128, 1);
        TILE(1, 31 * 128, 2);

        const int row0 = tm * 256 + wr * 128 + (lane >> 4) * 4;
        const int col0 = tn * 256 + wc * 128 + lane15;
        float sn8[8], z8[8];
#pragma unroll
        for (int ni = 0; ni < 8; ++ni) { sn8[ni] = sn[col0 + ni*16]; z8[ni] = zz[col0 + ni*16]; }
#pragma unroll
        for (int mi = 0; mi < 8; ++mi) {
            const int rbase = row0 + mi * 16;
            float sa4[4], Sf4[4];
#pragma unroll
            for (int j = 0; j < 4; ++j) { sa4[j] = sa[rbase + j]; Sf4[j] = (float)S[rbase + j]; }
#pragma unroll
            for (int ni = 0; ni < 8; ++ni) {
                const i32x4 v = acc[mi][ni];
                const int c = col0 + ni * 16;
#pragma unroll
                for (int j = 0; j < 4; ++j)
                    C[(size_t)(rbase + j) * NDIM + c] = sa4[j] * sn8[ni] * ((float)v[j] - z8[ni] * Sf4[j]);
            }
        }
    } else {
        // ============ TAIL: 128x256, tn 40..42 (192 blocks) ============
        const int h   = wg - 1280;
        const int tn  = 40 + (h % 3);
        const int tmh = h / 3;

        const char* aStageBase = (const char*)Aq + (size_t)(tmh * 128 + sRow) * KDIM + gColSwz;
        const char* bStageBase = (const char*)Bq + (size_t)(tn * 256 + sRow) * KDIM + gColSwz;

        const int aRdBase = wr * 8192 + lane15 * 128;    // wr*64 rows
        const int bRdBase = wc * 16384 + lane15 * 128;   // wc*128 cols

        i32x4 acc[4][8] = {};
        i32x4 aF[4][2];
        i32x4 bF[8][2];

        STAGE_TA(0, 0);
        STAGE_TB(0, 0);
        STAGE_TA(1, 128);
        WAITV(4);
        BAR();

        int kB = 0;
#pragma unroll 1
        for (int t = 0; t < 29; t += 2) {
            TTILE(0, kB, 0);
            TTILE(1, kB + 128, 0);
            kB += 256;
        }
        TTILE(0, 30 * 128, 1);
        TTILE(1, 31 * 128, 2);

        const int row0 = tmh * 128 + wr * 64 + (lane >> 4) * 4;
        const int col0 = tn * 256 + wc * 128 + lane15;
        float sn8[8], z8[8];
#pragma unroll
        for (int ni = 0; ni < 8; ++ni) { sn8[ni] = sn[col0 + ni*16]; z8[ni] = zz[col0 + ni*16]; }
#pragma unroll
        for (int mi = 0; mi < 4; ++mi) {
            const int rbase = row0 + mi * 16;
            float sa4[4], Sf4[4];
#pragma unroll
            for (int j = 0; j < 4; ++j) { sa4[j] = sa[rbase + j]; Sf4[j] = (float)S[rbase + j]; }
#pragma unroll
            for (int ni = 0; ni < 8; ++ni) {
                const i32x4 v = acc[mi][ni];
                const int c = col0 + ni * 16;
#pragma unroll
                for (int j = 0; j < 4; ++j)
                    C[(size_t)(rbase + j) * NDIM + c] = sa4[j] * sn8[ni] * ((float)v[j] - z8[ni] * Sf4[j]);
            }
        }
    }
}

extern "C" void kernel_launch(void* const* d_in, const int* in_sizes, int n_in,
                              void* d_out, int out_size, void* d_ws, size_t ws_size,
                              hipStream_t stream) {
    const float* x      = (const float*)d_in[0];
    const float* R      = (const float*)d_in[1];
    const float* scales = (const float*)d_in[2];
    const float* zeros  = (const float*)d_in[3];
    const int*   perm   = (const int*)d_in[4];
    const int*   qw     = (const int*)d_in[5];
    float*       out    = (float*)d_out;

    // workspace layout (bytes)
    char* ws = (char*)d_ws;
    unsigned short* xt16 = (unsigned short*)ws;                   //  64 MiB @ 0
    signed char*    xt8  = (signed char*)(ws + 67108864);         //  32 MiB
    signed char*    q8   = (signed char*)(ws + 100663296);        //  43 MiB
    float*          pmax = (float*)(ws + 145752064);              // 512 KiB
    float*          sa   = (float*)(ws + 146276352);              //  32 KiB
    int*            S    = (int*)(ws + 146309120);                //  32 KiB

    prep1_kernel<<<dim3(8192 + 11008), 256, 0, stream>>>(x, R, perm, qw, xt16, pmax, q8);
    pack_kernel<<<dim3(M_TOK), 256, 0, stream>>>(xt16, pmax, xt8, S, sa);
    gemm_all<<<dim3(1472), 256, 0, stream>>>(xt8, q8, scales, zeros, sa, S, out);
}

// Round 21
// 427.668 us; speedup vs baseline: 1.0713x; 1.0379x over previous
//
#include <hip/hip_runtime.h>
#include <hip/hip_bf16.h>
#include <stdint.h>

#define M_TOK 8192
#define KDIM  4096
#define NDIM  11008

typedef float  f32x4  __attribute__((ext_vector_type(4)));
typedef int    i32x4  __attribute__((ext_vector_type(4)));
typedef unsigned short ushort8 __attribute__((ext_vector_type(8)));

__device__ __forceinline__ unsigned short f2b(float f) {
    union { float f; unsigned int i; } v; v.f = f;
    unsigned int u = v.i;
    unsigned int r = (u + 0x7fffu + ((u >> 16) & 1u)) >> 16;
    return (unsigned short)r;
}
__device__ __forceinline__ float b2f(unsigned short u) {
    union { unsigned int i; float f; } v; v.i = ((unsigned int)u) << 16; return v.f;
}

__device__ __forceinline__ void gl_lds16(const void* g, void* l) {
    __builtin_amdgcn_global_load_lds(
        (const __attribute__((address_space(1))) unsigned int*)g,
        (__attribute__((address_space(3))) unsigned int*)l, 16, 0, 0);
}

// ---------------------------------------------------------------------------
// prep1 (round-15 verified): blocks 0..8191 rotate (+group max, vectorized
// contiguous-gather fast path), 8192..19199 qpack int32->i8.
// ---------------------------------------------------------------------------
__global__ __launch_bounds__(256) void prep1_kernel(
    const float* __restrict__ x, const float* __restrict__ R,
    const int* __restrict__ perm, const int* __restrict__ qw,
    unsigned short* __restrict__ xt, float* __restrict__ pmax,
    signed char* __restrict__ q8)
{
    const int bid = blockIdx.x;
    const int t   = threadIdx.x;

    if (bid < 8192) {
        __shared__ float Rs[16 * 273];
        __shared__ int   ps[256];
        const int bg = bid & 15;
        const int mc = bid >> 4;

        ps[t] = perm[bg * 256 + t];
        {
            const float* Rg = R + (size_t)bg * 4096;
#pragma unroll
            for (int k = 0; k < 16; ++k) {
                const int idx = t * 16 + k;
                const int bs = idx >> 8;
                const int i  = (idx >> 4) & 15;
                const int j  = idx & 15;
                Rs[bs * 273 + i * 17 + j] = Rg[idx];
            }
        }
        __syncthreads();

        const int bs = t & 15;
        const int r  = t >> 4;
        const int m  = mc * 16 + r;
        const float* xrow = x + (size_t)m * KDIM;

        const int base = ps[bs * 16];
        bool contig = (base & 3) == 0;
#pragma unroll
        for (int i = 1; i < 16; ++i) contig &= (ps[bs * 16 + i] == base + i);

        float xv[16];
        if (contig) {
            const f32x4* xp = (const f32x4*)(xrow + base);
            const f32x4 a0 = xp[0], a1 = xp[1], a2 = xp[2], a3 = xp[3];
#pragma unroll
            for (int i = 0; i < 4; ++i) {
                xv[i]      = a0[i];
                xv[4 + i]  = a1[i];
                xv[8 + i]  = a2[i];
                xv[12 + i] = a3[i];
            }
        } else {
#pragma unroll
            for (int i = 0; i < 16; ++i) xv[i] = xrow[ps[bs * 16 + i]];
        }

        float o[16];
#pragma unroll
        for (int j = 0; j < 16; ++j) o[j] = 0.f;
#pragma unroll
        for (int i = 0; i < 16; ++i) {
            const float xi = xv[i];
            const float* Rrow = &Rs[bs * 273 + i * 17];
#pragma unroll
            for (int j = 0; j < 16; ++j) o[j] += xi * Rrow[j];
        }

        float lm = 0.f;
#pragma unroll
        for (int j = 0; j < 16; ++j) lm = fmaxf(lm, fabsf(o[j]));
#pragma unroll
        for (int k = 1; k < 16; k <<= 1) lm = fmaxf(lm, __shfl_xor(lm, k, 64));
        if (bs == 0) pmax[(size_t)m * 16 + bg] = lm;

        unsigned short os[16] __attribute__((aligned(16)));
#pragma unroll
        for (int j = 0; j < 16; ++j) os[j] = f2b(o[j]);
        unsigned short* dst = xt + (size_t)m * KDIM + bg * 256 + bs * 16;
        *(ushort8*)dst       = *(ushort8*)os;
        *(ushort8*)(dst + 8) = *(ushort8*)(os + 8);
    } else {
        const size_t base = ((size_t)(bid - 8192) * 256 + t) * 16;
        const int4* qp = (const int4*)(qw + base);
        signed char o[16] __attribute__((aligned(16)));
#pragma unroll
        for (int c = 0; c < 4; ++c) {
            const int4 v = qp[c];
            o[c*4+0] = (signed char)v.x; o[c*4+1] = (signed char)v.y;
            o[c*4+2] = (signed char)v.z; o[c*4+3] = (signed char)v.w;
        }
        *(int4*)(q8 + base) = *(const int4*)o;
    }
}

// ---------------------------------------------------------------------------
// Pack (round-12 verified): per-row amax -> s_a[m]; bf16 -> i8; S[m].
// ---------------------------------------------------------------------------
__global__ __launch_bounds__(256) void pack_kernel(
    const unsigned short* __restrict__ xt, const float* __restrict__ pmax,
    signed char* __restrict__ xt8, int* __restrict__ S, float* __restrict__ sa)
{
    const int m = blockIdx.x;
    const int t = threadIdx.x;

    float am = 1e-20f;
#pragma unroll
    for (int i = 0; i < 16; ++i) am = fmaxf(am, pmax[(size_t)m * 16 + i]);
    const float inv = 127.0f / am;

    const unsigned short* src = xt + (size_t)m * KDIM + t * 16;
    ushort8 u0 = *(const ushort8*)src;
    ushort8 u1 = *(const ushort8*)(src + 8);
    signed char qv[16] __attribute__((aligned(16)));
    int s = 0;
#pragma unroll
    for (int i = 0; i < 8; ++i) {
        int q0 = (int)rintf(b2f(u0[i]) * inv);
        q0 = q0 > 127 ? 127 : (q0 < -127 ? -127 : q0);
        qv[i] = (signed char)q0; s += q0;
        int q1 = (int)rintf(b2f(u1[i]) * inv);
        q1 = q1 > 127 ? 127 : (q1 < -127 ? -127 : q1);
        qv[8 + i] = (signed char)q1; s += q1;
    }
    *(int4*)(xt8 + (size_t)m * KDIM + t * 16) = *(const int4*)qv;

#pragma unroll
    for (int k = 1; k < 64; k <<= 1) s += __shfl_xor(s, k, 64);
    __shared__ int ws[4];
    if ((t & 63) == 0) ws[t >> 6] = s;
    __syncthreads();
    if (t == 0) {
        S[m]  = ws[0] + ws[1] + ws[2] + ws[3];
        sa[m] = am * (1.0f / 127.0f);
    }
}

// ---------------------------------------------------------------------------
// i8 GEMM — round-12 verified config (333-340 us across rounds 12/14/15/18;
// the plateau of this structure family: six structural variants all lost).
// 256x256 tiles, BK=128, 8 waves, pipelined TILE with reg-dbuf frags,
// counted WAITV(4), 2 barriers/K-tile, 0-conflict XOR swizzle, merged tail.
// ---------------------------------------------------------------------------
#define BAR() do { asm volatile("" ::: "memory"); __builtin_amdgcn_s_barrier(); \
                   asm volatile("" ::: "memory"); } while (0)
#define WAITV(n) asm volatile("s_waitcnt vmcnt(" #n ")" ::: "memory")
#define PRIO1 __builtin_amdgcn_s_setprio(1)
#define PRIO0 __builtin_amdgcn_s_setprio(0)

#define ABASE(bb) ((bb)*65536)
#define BBASE(bb) ((bb)*65536 + 32768)

#define STAGE_A(bb, kB) do { \
    gl_lds16(aStageBase + (size_t)(  0)*KDIM + (kB), lds + ABASE(bb) +     0 + wOff); \
    gl_lds16(aStageBase + (size_t)( 64)*KDIM + (kB), lds + ABASE(bb) +  8192 + wOff); \
    gl_lds16(aStageBase + (size_t)(128)*KDIM + (kB), lds + ABASE(bb) + 16384 + wOff); \
    gl_lds16(aStageBase + (size_t)(192)*KDIM + (kB), lds + ABASE(bb) + 24576 + wOff); \
} while (0)
#define STAGE_B0(bb, kB) do { \
    gl_lds16(bStageBase + (size_t)(  0)*KDIM + (kB), lds + BBASE(bb) +     0 + wOff); \
    gl_lds16(bStageBase + (size_t)( 64)*KDIM + (kB), lds + BBASE(bb) +  8192 + wOff); \
} while (0)
#define STAGE_B1(bb, kB) do { \
    gl_lds16(bStageBase + (size_t)(128)*KDIM + (kB), lds + BBASE(bb) + 16384 + wOff); \
    gl_lds16(bStageBase + (size_t)(192)*KDIM + (kB), lds + BBASE(bb) + 24576 + wOff); \
} while (0)

#define PH_READ_A2(bb, mh, dst) do { \
    _Pragma("unroll") \
    for (int mf = 0; mf < 4; ++mf) { \
        dst[mf][0] = *(const i32x4*)(lds + ABASE(bb) + aRdBase + ((mh)*64 + mf*16)*128 + cs0); \
        dst[mf][1] = *(const i32x4*)(lds + ABASE(bb) + aRdBase + ((mh)*64 + mf*16)*128 + cs1); \
    } \
} while (0)
#define PH_READ_B2(bb, nh, dst) do { \
    _Pragma("unroll") \
    for (int nf = 0; nf < 2; ++nf) { \
        dst[nf][0] = *(const i32x4*)(lds + BBASE(bb) + bRdBase + ((nh)*32 + nf*16)*128 + cs0); \
        dst[nf][1] = *(const i32x4*)(lds + BBASE(bb) + bRdBase + ((nh)*32 + nf*16)*128 + cs1); \
    } \
} while (0)

#define MFMA_QX(mh, nh, Aset, Bset) do { \
    _Pragma("unroll") \
    for (int mf = 0; mf < 4; ++mf) \
    _Pragma("unroll") \
    for (int nf = 0; nf < 2; ++nf) { \
        acc[(mh)*4+mf][(nh)*2+nf] = __builtin_amdgcn_mfma_i32_16x16x64_i8( \
            Aset[mf][0], Bset[nf][0], acc[(mh)*4+mf][(nh)*2+nf], 0, 0, 0); \
        acc[(mh)*4+mf][(nh)*2+nf] = __builtin_amdgcn_mfma_i32_16x16x64_i8( \
            Aset[mf][1], Bset[nf][1], acc[(mh)*4+mf][(nh)*2+nf], 0, 0, 0); \
    } \
} while (0)

#define TILE(bb, kB, MODE) do { \
    PH_READ_A2(bb, 0, aF0); PH_READ_B2(bb, 0, bG0); \
    if ((MODE) <= 1) STAGE_B0((bb)^1, (kB) + 128); \
    PH_READ_B2(bb, 1, bG1); \
    PRIO1; MFMA_QX(0, 0, aF0, bG0); PRIO0; \
    if ((MODE) <= 1) STAGE_B1((bb)^1, (kB) + 128); \
    PH_READ_A2(bb, 1, aF1); \
    PRIO1; MFMA_QX(0, 1, aF0, bG1); PRIO0; \
    BAR(); \
    if ((MODE) == 0) STAGE_A(bb, (kB) + 256); \
    PRIO1; MFMA_QX(1, 0, aF1, bG0); PRIO0; \
    PRIO1; MFMA_QX(1, 1, aF1, bG1); PRIO0; \
    if ((MODE) == 0) WAITV(4); \
    if ((MODE) == 1) WAITV(0); \
    BAR(); \
} while (0)

// tail (128x256) path
#define TAB(bb) ((bb)*16384)
#define TBB(bb) (32768 + (bb)*32768)

#define STAGE_TA(bb, kB) do { \
    gl_lds16(aStageBase + (size_t)(  0)*KDIM + (kB), lds + TAB(bb) +    0 + wOff); \
    gl_lds16(aStageBase + (size_t)( 64)*KDIM + (kB), lds + TAB(bb) + 8192 + wOff); \
} while (0)
#define STAGE_TB0(bb, kB) do { \
    gl_lds16(bStageBase + (size_t)(  0)*KDIM + (kB), lds + TBB(bb) +     0 + wOff); \
    gl_lds16(bStageBase + (size_t)( 64)*KDIM + (kB), lds + TBB(bb) +  8192 + wOff); \
} while (0)
#define STAGE_TB1(bb, kB) do { \
    gl_lds16(bStageBase + (size_t)(128)*KDIM + (kB), lds + TBB(bb) + 16384 + wOff); \
    gl_lds16(bStageBase + (size_t)(192)*KDIM + (kB), lds + TBB(bb) + 24576 + wOff); \
} while (0)

#define PH_READ_TA(bb) do { \
    _Pragma("unroll") \
    for (int mf = 0; mf < 4; ++mf) { \
        aF[mf][0] = *(const i32x4*)(lds + TAB(bb) + aRdBase + (mf*16)*128 + cs0); \
        aF[mf][1] = *(const i32x4*)(lds + TAB(bb) + aRdBase + (mf*16)*128 + cs1); \
    } \
} while (0)
#define PH_READ_TB(bb, nh) do { \
    _Pragma("unroll") \
    for (int nf = 0; nf < 2; ++nf) { \
        bF[nh][nf][0] = *(const i32x4*)(lds + TBB(bb) + bRdBase + ((nh)*32 + nf*16)*128 + cs0); \
        bF[nh][nf][1] = *(const i32x4*)(lds + TBB(bb) + bRdBase + ((nh)*32 + nf*16)*128 + cs1); \
    } \
} while (0)

#define MFMA_TQ(nh) do { \
    _Pragma("unroll") \
    for (int mf = 0; mf < 4; ++mf) \
    _Pragma("unroll") \
    for (int nf = 0; nf < 2; ++nf) { \
        acc[mf][(nh)*2+nf] = __builtin_amdgcn_mfma_i32_16x16x64_i8( \
            aF[mf][0], bF[nh][nf][0], acc[mf][(nh)*2+nf], 0, 0, 0); \
        acc[mf][(nh)*2+nf] = __builtin_amdgcn_mfma_i32_16x16x64_i8( \
            aF[mf][1], bF[nh][nf][1], acc[mf][(nh)*2+nf], 0, 0, 0); \
    } \
} while (0)

#define TTILE(bb, kB, MODE) do { \
    PH_READ_TA(bb); PH_READ_TB(bb, 0); \
    if ((MODE) <= 1) STAGE_TB0((bb)^1, (kB) + 128); \
    BAR(); PRIO1; MFMA_TQ(0); PRIO0; BAR(); \
    PH_READ_TB(bb, 1); \
    if ((MODE) <= 1) STAGE_TB1((bb)^1, (kB) + 128); \
    BAR(); PRIO1; MFMA_TQ(1); PRIO0; \
    if ((MODE) == 0) STAGE_TA(bb, (kB) + 256); \
    if ((MODE) == 0) WAITV(2); \
    if ((MODE) == 1) WAITV(0); \
    BAR(); \
} while (0)

__global__ __launch_bounds__(512, 2) void gemm_all(
    const signed char* __restrict__ Aq, const signed char* __restrict__ Bq,
    const float* __restrict__ sn, const float* __restrict__ zz,
    const float* __restrict__ sa, const int* __restrict__ S,
    float* __restrict__ C)
{
    __shared__ char lds[131072];

    const int tid  = threadIdx.x;
    const int wave = tid >> 6;
    const int lane = tid & 63;
    const int wr   = wave >> 2;
    const int wc   = wave & 3;
    const int wg   = blockIdx.x;

    const int gRow    = wave * 8 + (lane >> 3);
    const int gColSwz = (((lane & 7) ^ ((lane >> 3) & 7)) << 4);
    const int wOff    = wave * 1024;

    const int laneRow128 = (lane & 15) * 128;
    const int lx  = (lane & 7) << 4;
    const int cs0 = (((lane >> 4) * 16)      ) ^ lx;   // k 0..63
    const int cs1 = (((lane >> 4) * 16) + 64 ) ^ lx;   // k 64..127

    if (wg < 1280) {
        // ================= MAIN: 256x256, tn 0..39 =================
        const int swz = (wg & 7) * 160 + (wg >> 3);
        const int Sx = swz >> 7;
        const int L  = swz & 127;
        const int tm = L >> 2;
        const int tn = (Sx << 2) + (L & 3);

        const char* aStageBase = (const char*)Aq + (size_t)(tm * 256 + gRow) * KDIM + gColSwz;
        const char* bStageBase = (const char*)Bq + (size_t)(tn * 256 + gRow) * KDIM + gColSwz;

        const int aRdBase = wr * 16384 + laneRow128;
        const int bRdBase = (wc >> 1) * 16384 + (wc & 1) * 8192 + laneRow128;

        i32x4 acc[8][4] = {};
        i32x4 aF0[4][2], aF1[4][2];
        i32x4 bG0[2][2], bG1[2][2];

        STAGE_A(0, 0);
        STAGE_B0(0, 0); STAGE_B1(0, 0);
        STAGE_A(1, 128);
        WAITV(4);
        BAR();

        int kB = 0;
#pragma unroll 1
        for (int t = 0; t < 29; t += 2) {       // 32 K-tiles of BK=128
            TILE(0, kB, 0);
            TILE(1, kB + 128, 0);
            kB += 256;
        }
        TILE(0, 30 * 128, 1);
        TILE(1, 31 * 128, 2);

        const int row0 = tm * 256 + wr * 128 + (lane >> 4) * 4;
        const int col0 = tn * 256 + wc * 64 + (lane & 15);
        float sn4[4], z4[4];
#pragma unroll
        for (int ni = 0; ni < 4; ++ni) { sn4[ni] = sn[col0 + ni*16]; z4[ni] = zz[col0 + ni*16]; }
#pragma unroll
        for (int mi = 0; mi < 8; ++mi) {
            const int rbase = row0 + mi * 16;
            float sa4[4], Sf4[4];
#pragma unroll
            for (int j = 0; j < 4; ++j) { sa4[j] = sa[rbase + j]; Sf4[j] = (float)S[rbase + j]; }
#pragma unroll
            for (int ni = 0; ni < 4; ++ni) {
                const i32x4 v = acc[mi][ni];
                const int c = col0 + ni * 16;
#pragma unroll
                for (int j = 0; j < 4; ++j)
                    C[(size_t)(rbase + j) * NDIM + c] = sa4[j] * sn4[ni] * ((float)v[j] - z4[ni] * Sf4[j]);
            }
        }
    } else {
        // ================= TAIL: 128x256, tn 40..42 =================
        const int h   = wg - 1280;
        const int tn  = 40 + (h % 3);
        const int tmh = h / 3;

        const char* aStageBase = (const char*)Aq + (size_t)(tmh * 128 + gRow) * KDIM + gColSwz;
        const char* bStageBase = (const char*)Bq + (size_t)(tn * 256 + gRow) * KDIM + gColSwz;

        const int aRdBase = wr * 8192 + laneRow128;
        const int bRdBase = (wc >> 1) * 16384 + (wc & 1) * 8192 + laneRow128;

        i32x4 acc[4][4] = {};
        i32x4 aF[4][2];
        i32x4 bF[2][2][2];

        STAGE_TA(0, 0);
        STAGE_TB0(0, 0); STAGE_TB1(0, 0);
        STAGE_TA(1, 128);
        WAITV(2);
        BAR();

        int kB = 0;
#pragma unroll 1
        for (int t = 0; t < 29; t += 2) {
            TTILE(0, kB, 0);
            TTILE(1, kB + 128, 0);
            kB += 256;
        }
        TTILE(0, 30 * 128, 1);
        TTILE(1, 31 * 128, 2);

        const int row0 = tmh * 128 + wr * 64 + (lane >> 4) * 4;
        const int col0 = tn * 256 + wc * 64 + (lane & 15);
        float sn4[4], z4[4];
#pragma unroll
        for (int ni = 0; ni < 4; ++ni) { sn4[ni] = sn[col0 + ni*16]; z4[ni] = zz[col0 + ni*16]; }
#pragma unroll
        for (int mi = 0; mi < 4; ++mi) {
            const int rbase = row0 + mi * 16;
            float sa4[4], Sf4[4];
#pragma unroll
            for (int j = 0; j < 4; ++j) { sa4[j] = sa[rbase + j]; Sf4[j] = (float)S[rbase + j]; }
#pragma unroll
            for (int ni = 0; ni < 4; ++ni) {
                const i32x4 v = acc[mi][ni];
                const int c = col0 + ni * 16;
#pragma unroll
                for (int j = 0; j < 4; ++j)
                    C[(size_t)(rbase + j) * NDIM + c] = sa4[j] * sn4[ni] * ((float)v[j] - z4[ni] * Sf4[j]);
            }
        }
    }
}

extern "C" void kernel_launch(void* const* d_in, const int* in_sizes, int n_in,
                              void* d_out, int out_size, void* d_ws, size_t ws_size,
                              hipStream_t stream) {
    const float* x      = (const float*)d_in[0];
    const float* R      = (const float*)d_in[1];
    const float* scales = (const float*)d_in[2];
    const float* zeros  = (const float*)d_in[3];
    const int*   perm   = (const int*)d_in[4];
    const int*   qw     = (const int*)d_in[5];
    float*       out    = (float*)d_out;

    // workspace layout (bytes)
    char* ws = (char*)d_ws;
    unsigned short* xt16 = (unsigned short*)ws;                   //  64 MiB @ 0
    signed char*    xt8  = (signed char*)(ws + 67108864);         //  32 MiB
    signed char*    q8   = (signed char*)(ws + 100663296);        //  43 MiB
    float*          pmax = (float*)(ws + 145752064);              // 512 KiB
    float*          sa   = (float*)(ws + 146276352);              //  32 KiB
    int*            S    = (int*)(ws + 146309120);                //  32 KiB

    prep1_kernel<<<dim3(8192 + 11008), 256, 0, stream>>>(x, R, perm, qw, xt16, pmax, q8);
    pack_kernel<<<dim3(M_TOK), 256, 0, stream>>>(xt16, pmax, xt8, S, sa);
    gemm_all<<<dim3(1472), 512, 0, stream>>>(xt8, q8, scales, zeros, sa, S, out);
}